// Round 3
// baseline (3936.679 us; speedup 1.0000x reference)
//
#include <hip/hip_runtime.h>

// VQBlock: x[16,64,64,256] fp32, dict[256,1024] fp32.
// out = concat(q_st flat [16777216], loss [1]) fp32.
//
// Round 5 structure (barrier-free):
//  - f16 MFMA fast path (16x16x32_f16), M=32 rows/wave, B fragments read
//    DIRECTLY from L2-resident packB (512 KB) -- no LDS staging, no
//    __syncthreads anywhere in k_vq. Round-2 lesson: the compiler's
//    structural vmcnt(0) drain before s_barrier nullifies LDS prefetch and
//    the dbuf LDS halved occupancy; this kernel deletes the whole class.
//  - Raw (non-draining) s_barrier once per chunk as pacing only, to keep the
//    block's 4 waves reading the same packB chunk (L1 reuse). No data dep.
//  - Packed-u32 top-2 selection (proven round 4): pk = bits(dn+8-2acc)&~1023 | k.
//    EPS_TIE 6e-3 covers f16 err + pack truncation as before.
//  - Wave-local everything after the chunk loop: shuffle top-2 merge, per-wave
//    np-fp32-faithful rescan of ambiguous rows (identical per-code arithmetic),
//    per-wave epilogue (rows wrow..wrow+31), per-wave double loss partial.
//  - q_st written as fl(x + fl(q-x)) to match np exactly.

#define NROWS   65536
#define DIM     256
#define NCODE   1024
#define WROWS   32                  // rows per wave
#define RPB     128                 // 4 waves per block
#define NBLK    (NROWS / RPB)       // 512
#define NWAVE   (NROWS / WROWS)     // 2048
#define EPS_TIE 6e-3f

typedef _Float16 half8 __attribute__((ext_vector_type(8)));
typedef float    f32x4 __attribute__((ext_vector_type(4)));

// ---------- merged prep kernel ----------
// transpose + f16 MFMA-B pack + (blocks 0-3) dictnorm with +8 bias baked in.
__global__ void k_prep(const float* __restrict__ dict, float* __restrict__ dictT,
                       float* __restrict__ dictnorm, unsigned short* __restrict__ packB) {
    int gid = blockIdx.x * 256 + threadIdx.x;          // grid 256 x 256
#pragma unroll
    for (int ii = 0; ii < 4; ++ii) {
        int o = ii * 65536 + gid;
        // transpose (coalesced read)
        { int d = o >> 10, k = o & 1023; dictT[k * DIM + d] = dict[o]; }
        // pack -> packB[kk*32768 + n*32 + q*8 + j] = f16(dict[(kk*32+q*8+j)][n])
        { int j = o & 7, q = (o >> 3) & 3, n = (o >> 5) & 1023, kk = o >> 15;
          int d = kk * 32 + q * 8 + j;
          _Float16 h = (_Float16)dict[d * NCODE + n];   // RTN cvt
          packB[o] = *(unsigned short*)&h; }
    }
    if (blockIdx.x < 4) {
        int k = blockIdx.x * 256 + threadIdx.x;
        float s = 0.f;
#pragma unroll 8
        for (int d = 0; d < DIM; ++d) {
            float v = dict[d * NCODE + k];
            s = fmaf(v, v, s);
        }
        dictnorm[k] = s + 8.0f;    // bias for packed-selection positivity; cancels in gaps
    }
}

// np pairwise sum of squares of 128 contiguous elements
__device__ __forceinline__ float np_pairwise_sq_128(const float* a, int stride) {
    float r[8];
#pragma unroll
    for (int j = 0; j < 8; ++j) {
        float v = a[j * stride];
        r[j] = __fmul_rn(v, v);
    }
    for (int i = 8; i < 128; i += 8) {
#pragma unroll
        for (int j = 0; j < 8; ++j) {
            float v = a[(i + j) * stride];
            r[j] = __fadd_rn(r[j], __fmul_rn(v, v));
        }
    }
    return __fadd_rn(__fadd_rn(__fadd_rn(r[0], r[1]), __fadd_rn(r[2], r[3])),
                     __fadd_rn(__fadd_rn(r[4], r[5]), __fadd_rn(r[6], r[7])));
}

// ---------- main kernel (no LDS, no __syncthreads) ----------

__global__ __launch_bounds__(256, 2) void k_vq(
    const float* __restrict__ x, const float* __restrict__ dict,
    const float* __restrict__ dictT, const float* __restrict__ dictnorm,
    const unsigned short* __restrict__ packB,
    float* __restrict__ out, double* __restrict__ wave_sums)
{
    const int tid  = threadIdx.x;
    const int ln   = tid & 63, wv = tid >> 6;
    const int l15  = ln & 15, q = ln >> 4;
    const int wrow = blockIdx.x * RPB + wv * WROWS;   // this wave's 32 rows
    const int gwave = blockIdx.x * 4 + wv;

    // A fragments: 2 mtiles x 8 k-slices, register-resident for all 16 chunks.
    // lane provides A row m=l15 of mtile u (x row wrow + u*16 + l15), k = kk*32 + q*8 + j
    half8 afrag[2][8];
#pragma unroll
    for (int u = 0; u < 2; ++u) {
        const float* ar = x + (size_t)(wrow + u * 16 + l15) * DIM + q * 8;
#pragma unroll
        for (int kk = 0; kk < 8; ++kk) {
            const float4 p0 = *(const float4*)(ar + kk * 32);
            const float4 p1 = *(const float4*)(ar + kk * 32 + 4);
            half8 h;
            h[0] = (_Float16)p0.x; h[1] = (_Float16)p0.y; h[2] = (_Float16)p0.z; h[3] = (_Float16)p0.w;
            h[4] = (_Float16)p1.x; h[5] = (_Float16)p1.y; h[6] = (_Float16)p1.z; h[7] = (_Float16)p1.w;
            afrag[u][kk] = h;
        }
    }

    // packed top-2 per lane for its 8 C-rows (u in 2, i in 4)
    unsigned p1v[2][4], p2v[2][4];
#pragma unroll
    for (int u = 0; u < 2; ++u)
#pragma unroll
        for (int i = 0; i < 4; ++i) { p1v[u][i] = 0xFFFFFFFFu; p2v[u][i] = 0xFFFFFFFFu; }

    // per-lane B base: code n contributes (n*32 + q*8) shorts; lane handles n = c0 + t*16 + l15
    const unsigned short* bbase = packB + l15 * 32 + q * 8;

    for (int cc = 0; cc < 16; ++cc) {
        const int c0 = cc * 64;
        float dn[4];
#pragma unroll
        for (int t = 0; t < 4; ++t) dn[t] = dictnorm[c0 + t * 16 + l15];   // ||d||^2 + 8

        const f32x4 zero = {0.f, 0.f, 0.f, 0.f};
        f32x4 acc[2][4];
#pragma unroll
        for (int u = 0; u < 2; ++u)
#pragma unroll
            for (int t = 0; t < 4; ++t) acc[u][t] = zero;

#pragma unroll
        for (int kk = 0; kk < 8; ++kk) {
            const unsigned short* bk_ = bbase + (size_t)kk * 32768 + c0 * 32;
#pragma unroll
            for (int t = 0; t < 4; ++t) {
                // dense coalesced 1KB/wave load, L2-resident (packB = 512 KB)
                const half8 b = *(const half8*)(bk_ + t * 512);
                acc[0][t] = __builtin_amdgcn_mfma_f32_16x16x32_f16(afrag[0][kk], b, acc[0][t], 0, 0, 0);
                acc[1][t] = __builtin_amdgcn_mfma_f32_16x16x32_f16(afrag[1][kk], b, acc[1][t], 0, 0, 0);
            }
        }

        // packed top-2 update: branchless, index-ascending tiebreak
#pragma unroll
        for (int t = 0; t < 4; ++t) {
            const unsigned kbase = (unsigned)(c0 + t * 16 + l15);
#pragma unroll
            for (int u = 0; u < 2; ++u)
#pragma unroll
                for (int i = 0; i < 4; ++i) {
                    const float s = fmaf(-2.f, acc[u][t][i], dn[t]);      // in (1.8, 14.6)
                    const unsigned pk = (__float_as_uint(s) & 0xFFFFFC00u) | kbase;
                    const unsigned mx = p1v[u][i] > pk ? p1v[u][i] : pk;
                    p2v[u][i] = p2v[u][i] < mx ? p2v[u][i] : mx;
                    p1v[u][i] = p1v[u][i] < pk ? p1v[u][i] : pk;
                }
        }
        __builtin_amdgcn_s_barrier();   // pacing only (no data dep, no drain needed)
    }

    // top-2 merge across the 16 lanes sharing quad q; butterfly leaves result on ALL lanes
    unsigned a1m[2][4]; float gapm[2][4];
#pragma unroll
    for (int u = 0; u < 2; ++u)
#pragma unroll
        for (int i = 0; i < 4; ++i) {
            unsigned a1 = p1v[u][i], a2 = p2v[u][i];
#pragma unroll
            for (int m = 1; m < 16; m <<= 1) {
                const unsigned o1 = __shfl_xor(a1, m);
                const unsigned o2 = __shfl_xor(a2, m);
                const unsigned mx = a1 > o1 ? a1 : o1;
                a1 = a1 < o1 ? a1 : o1;
                const unsigned mn2 = a2 < o2 ? a2 : o2;
                a2 = mx < mn2 ? mx : mn2;
            }
            a1m[u][i] = a1;
            gapm[u][i] = __uint_as_float(a2 & 0xFFFFFC00u) - __uint_as_float(a1 & 0xFFFFFC00u);
        }

    // gather per-row winner + ambiguity mask (wave-uniform). row rr = u*16 + q*4 + i
    int k1r[32]; unsigned ambmask = 0u;
#pragma unroll
    for (int rr = 0; rr < 32; ++rr) {
        const int src = ((rr >> 2) & 3) * 16;
        k1r[rr] = __shfl((int)(a1m[rr >> 4][rr & 3] & 1023u), src);
        const float g = __shfl(gapm[rr >> 4][rr & 3], src);
        ambmask |= (g < EPS_TIE ? 1u : 0u) << rr;
    }

    // np-fp32-faithful full rescan of ambiguous rows (wave-local, uniform branch)
    while (ambmask) {
        const int rr = __builtin_ctz(ambmask); ambmask &= ambmask - 1u;
        const float* xr = x + (size_t)(wrow + rr) * DIM;
        const float nf = __fadd_rn(np_pairwise_sq_128(xr, 1), np_pairwise_sq_128(xr + 128, 1));
        float bd = 3.4e38f; int bk = 0x7fffffff;
        for (int c = 0; c < 16; ++c) {
            const int k = c * 64 + ln;                    // coalesced dict reads
            float sim = 0.f, nd = 0.f;
            for (int d = 0; d < DIM; ++d) {
                const float dv = dict[(size_t)d * NCODE + k];
                const float fv = xr[d];                    // broadcast (L1)
                sim = fmaf(fv, dv, sim);                   // BLAS-style FMA chain, d asc
                nd  = __fadd_rn(nd, __fmul_rn(dv, dv));    // np axis-0 reduce
            }
            const float dist = __fsub_rn(__fadd_rn(nf, nd), __fmul_rn(2.f, sim));
            if (dist < bd) { bd = dist; bk = k; }
        }
#pragma unroll
        for (int m = 1; m < 64; m <<= 1) {
            const float od = __shfl_xor(bd, m);
            const int   ok = __shfl_xor(bk, m);
            if (od < bd || (od == bd && ok < bk)) { bd = od; bk = ok; }
        }
        // static-index update of k1r (rule #20: no runtime array indexing)
#pragma unroll
        for (int rr2 = 0; rr2 < 32; ++rr2)
            k1r[rr2] = (rr2 == rr) ? bk : k1r[rr2];
    }

    // epilogue (wave-local): q = 0.5*dictT[kstar]; out = fl(x + fl(q-x)); loss partial
    float lsum = 0.f;
#pragma unroll
    for (int rr = 0; rr < 32; ++rr) {
        const size_t e = (size_t)(wrow + rr) * DIM + ln * 4;
        const float4 dv = *(const float4*)&dictT[(size_t)k1r[rr] * DIM + ln * 4];
        const float4 xv = *(const float4*)&x[e];
        float4 qv; qv.x = 0.5f * dv.x; qv.y = 0.5f * dv.y; qv.z = 0.5f * dv.z; qv.w = 0.5f * dv.w;
        float4 ov;
        ov.x = __fadd_rn(xv.x, __fsub_rn(qv.x, xv.x));
        ov.y = __fadd_rn(xv.y, __fsub_rn(qv.y, xv.y));
        ov.z = __fadd_rn(xv.z, __fsub_rn(qv.z, xv.z));
        ov.w = __fadd_rn(xv.w, __fsub_rn(qv.w, xv.w));
        const float e0 = __fsub_rn(xv.x, qv.x), e1 = __fsub_rn(xv.y, qv.y);
        const float e2 = __fsub_rn(xv.z, qv.z), e3 = __fsub_rn(xv.w, qv.w);
        lsum += e0 * e0 + e1 * e1 + e2 * e2 + e3 * e3;
        *(float4*)&out[e] = ov;
    }

#pragma unroll
    for (int sft = 32; sft > 0; sft >>= 1) lsum += __shfl_down(lsum, sft, 64);
    if (ln == 0) wave_sums[gwave] = (double)lsum;
}

// ---------- loss finalize ----------

__global__ void k_finalize(const double* __restrict__ wave_sums, float* __restrict__ out_loss) {
    __shared__ double w[16];
    const int t = threadIdx.x;                  // 1024 threads
    double v = wave_sums[t] + wave_sums[t + 1024];
#pragma unroll
    for (int sft = 32; sft > 0; sft >>= 1) v += __shfl_down(v, sft, 64);
    if ((t & 63) == 0) w[t >> 6] = v;
    __syncthreads();
    if (t == 0) {
        double tot = 0.0;
        for (int i = 0; i < 16; ++i) tot += w[i];
        out_loss[0] = (float)(1.25 * tot / (double)(NROWS * DIM));
    }
}

// ---------- launch ----------

extern "C" void kernel_launch(void* const* d_in, const int* in_sizes, int n_in,
                              void* d_out, int out_size, void* d_ws, size_t ws_size,
                              hipStream_t stream) {
    (void)in_sizes; (void)n_in; (void)out_size; (void)ws_size;
    const float* x    = (const float*)d_in[0];
    const float* dict = (const float*)d_in[1];
    float* out = (float*)d_out;

    char* ws = (char*)d_ws;
    float*          dictT      = (float*)ws;                          // 1 MB
    float*          dictnorm   = (float*)(ws + 1048576);              // 4 KB
    double*         wave_sums  = (double*)(ws + 1048576 + 4096);      // 16 KB
    unsigned short* packB      = (unsigned short*)(ws + 1048576 + 4096 + 16384); // 512 KB

    k_prep<<<256, 256, 0, stream>>>(dict, dictT, dictnorm, packB);
    k_vq<<<NBLK, 256, 0, stream>>>(x, dict, dictT, dictnorm, packB, out, wave_sums);
    k_finalize<<<1, 1024, 0, stream>>>(wave_sums, out + (size_t)NROWS * DIM);
}